// Round 1
// baseline (269.786 us; speedup 1.0000x reference)
//
#include <hip/hip_runtime.h>
#include <hip/hip_bf16.h>

#define BB 32
#define SS 4096
#define DD 128
#define HH 8

typedef __attribute__((ext_vector_type(8))) short short8;   // 8 bf16 = 4 VGPRs (MFMA A/B frag)
typedef __attribute__((ext_vector_type(4))) float f32x4;    // MFMA C/D frag

// fp32 -> bf16 round-to-nearest-even (bit pattern)
__device__ inline unsigned short f2b(float f){
  unsigned int u = __float_as_uint(f);
  return (unsigned short)((u + 0x7fffu + ((u >> 16) & 1u)) >> 16);
}

// Swizzled element index in a [R][128] bf16 LDS tile.
// 8-element (16B) column blocks XOR'd with row&7 -> conflict-free ds_read_b128
// of 16 consecutive rows (the NT fragment pattern).
__device__ inline int swzi(int r, int c){
  return (r << 7) | (((c >> 3) ^ (r & 7)) << 3) | (c & 7);
}

// Load one MFMA A/B fragment: row-major NT tile, lane l -> row (base + l&15),
// 8 consecutive k at kblk*8. kblk in [0,16).
__device__ inline short8 ldfrag(const short* buf, int row, int kblk){
  return *reinterpret_cast<const short8*>(&buf[(row << 7) | ((kblk ^ (row & 7)) << 3)]);
}

// Stage a row-major fp32 [R][128] matrix from global into swizzled bf16 LDS.
// float4 reads (coalesced), ds_write_b64 (conflict-free: writes run along rows).
template<int R>
__device__ inline void stage_rows(const float* __restrict__ src, short* dst, int t){
  const float4* s4 = reinterpret_cast<const float4*>(src);
  #pragma unroll
  for (int f4 = t; f4 < R * 32; f4 += 256){
    int r = f4 >> 5, c = (f4 & 31) << 2;     // c % 4 == 0 -> all 4 elems in one 8-block
    float4 v = s4[f4];
    unsigned long long w =
        (unsigned long long)f2b(v.x)
      | ((unsigned long long)f2b(v.y) << 16)
      | ((unsigned long long)f2b(v.z) << 32)
      | ((unsigned long long)f2b(v.w) << 48);
    *reinterpret_cast<unsigned long long*>(&dst[swzi(r, c)]) = w;
  }
}

// 64x64 wave tile: C[wm..wm+63][wn..wn+63] += A(64 rows from bufA) * B^T(64 rows from bufB), K=128
__device__ inline void wave_gemm64(const short* bufA, const short* bufB,
                                   int wm, int wn, int lane, f32x4 acc[4][4]){
  #pragma unroll
  for (int ks = 0; ks < 4; ++ks){
    int kblk = ks * 4 + (lane >> 4);
    short8 af[4], bf[4];
    #pragma unroll
    for (int mt = 0; mt < 4; ++mt) af[mt] = ldfrag(bufA, wm + mt * 16 + (lane & 15), kblk);
    #pragma unroll
    for (int nt = 0; nt < 4; ++nt) bf[nt] = ldfrag(bufB, wn + nt * 16 + (lane & 15), kblk);
    #pragma unroll
    for (int mt = 0; mt < 4; ++mt)
      #pragma unroll
      for (int nt = 0; nt < 4; ++nt)
        acc[mt][nt] = __builtin_amdgcn_mfma_f32_16x16x32_bf16(af[mt], bf[nt], acc[mt][nt], 0, 0, 0);
  }
}

// ---------------- Kernel 1: G[b] = x[b]^T x[b] (fp32 accumulate via atomics) ----------------
// grid (8, B): blockIdx.x = K-split slot (512 s-rows), blockIdx.y = batch.
__global__ __launch_bounds__(256) void k_gram(const float* __restrict__ x, float* __restrict__ G){
  __shared__ short xsT[128 * 128];   // 32 KB, x^T chunk: [e][s'] swizzled
  const int t = threadIdx.x, lane = t & 63, wid = t >> 6;
  const int b = blockIdx.y;
  const int sbase = blockIdx.x * 512;
  const int wm = (wid >> 1) * 64, wn = (wid & 1) * 64;

  f32x4 acc[4][4];
  const f32x4 z = {0.f, 0.f, 0.f, 0.f};
  #pragma unroll
  for (int i = 0; i < 4; ++i)
    #pragma unroll
    for (int j = 0; j < 4; ++j) acc[i][j] = z;

  const float* xb = x + (size_t)b * SS * DD;
  for (int c = 0; c < 4; ++c){
    const float* src = xb + (size_t)(sbase + c * 128) * DD;
    __syncthreads();   // previous iter's MFMA reads done before overwrite
    // transpose-stage: lane-consecutive e (coalesced row reads), pack s-pairs -> b32 writes
    {
      int e = t & 127;
      int half = t >> 7;
      #pragma unroll
      for (int it = 0; it < 32; ++it){
        int s2 = it * 2 + half;                 // s-pair index 0..63
        float a0 = src[(2 * s2) * DD + e];
        float a1 = src[(2 * s2 + 1) * DD + e];
        unsigned int w = (unsigned)f2b(a0) | ((unsigned)f2b(a1) << 16);
        *reinterpret_cast<unsigned int*>(&xsT[swzi(e, 2 * s2)]) = w;
      }
    }
    __syncthreads();
    wave_gemm64(xsT, xsT, wm, wn, lane, acc);   // G tile: A = x^T rows e, B^T = x^T rows f
  }

  float* Gb = G + (size_t)b * DD * DD;
  #pragma unroll
  for (int mt = 0; mt < 4; ++mt)
    #pragma unroll
    for (int nt = 0; nt < 4; ++nt)
      #pragma unroll
      for (int i = 0; i < 4; ++i){
        int e = wm + mt * 16 + ((lane >> 4) << 2) + i;
        int f = wn + nt * 16 + (lane & 15);
        atomicAdd(&Gb[(e << 7) + f], acc[mt][nt][i]);
      }
}

// ---------------- Kernel 2: Mt[b][g][d] = sum_h (Wkq[h] G[b] Wv[h]^T)[d][g] ----------------
// grid (H, B). Step1: Tt = Wv[h] * G^T (NT). Step2: P = Wkq[h] * Tt^T (NT). Atomic into M^T.
__global__ __launch_bounds__(256) void k_heads(const float* __restrict__ G,
                                               const float* __restrict__ Wkq,
                                               const float* __restrict__ Wv,
                                               float* __restrict__ Mt){
  __shared__ short bufW[128 * 128];
  __shared__ short bufG[128 * 128];
  __shared__ short bufT[128 * 128];
  const int t = threadIdx.x, lane = t & 63, wid = t >> 6;
  const int h = blockIdx.x, b = blockIdx.y;
  const int wm = (wid >> 1) * 64, wn = (wid & 1) * 64;
  const f32x4 z = {0.f, 0.f, 0.f, 0.f};

  stage_rows<128>(Wv + (size_t)h * DD * DD, bufW, t);
  stage_rows<128>(G + (size_t)b * DD * DD, bufG, t);
  __syncthreads();

  f32x4 acc[4][4];
  #pragma unroll
  for (int i = 0; i < 4; ++i)
    #pragma unroll
    for (int j = 0; j < 4; ++j) acc[i][j] = z;
  // Tt[g][e] = sum_f Wv[g][f] * G[e][f]
  wave_gemm64(bufW, bufG, wm, wn, lane, acc);
  __syncthreads();   // all reads of bufW/bufG done

  // write Tt (bf16, swizzled) ; restage bufW with Wkq
  #pragma unroll
  for (int mt = 0; mt < 4; ++mt)
    #pragma unroll
    for (int nt = 0; nt < 4; ++nt)
      #pragma unroll
      for (int i = 0; i < 4; ++i){
        int g = wm + mt * 16 + ((lane >> 4) << 2) + i;
        int e = wn + nt * 16 + (lane & 15);
        bufT[swzi(g, e)] = (short)f2b(acc[mt][nt][i]);
      }
  stage_rows<128>(Wkq + (size_t)h * DD * DD, bufW, t);
  __syncthreads();

  #pragma unroll
  for (int i = 0; i < 4; ++i)
    #pragma unroll
    for (int j = 0; j < 4; ++j) acc[i][j] = z;
  // P[d][g] = sum_e Wkq[d][e] * Tt[g][e]
  wave_gemm64(bufW, bufT, wm, wn, lane, acc);

  float* Mb = Mt + (size_t)b * DD * DD;
  #pragma unroll
  for (int mt = 0; mt < 4; ++mt)
    #pragma unroll
    for (int nt = 0; nt < 4; ++nt)
      #pragma unroll
      for (int i = 0; i < 4; ++i){
        int d = wm + mt * 16 + ((lane >> 4) << 2) + i;
        int g = wn + nt * 16 + (lane & 15);
        atomicAdd(&Mb[(g << 7) + d], acc[mt][nt][i]);   // transposed store: Mt[g][d]
      }
}

// ---------------- Kernel 3: out[b][s][g] = sum_d x[b][s][d] * Mt[b][g][d] ----------------
// grid (S/128, B)
__global__ __launch_bounds__(256) void k_out(const float* __restrict__ x,
                                             const float* __restrict__ Mt,
                                             float* __restrict__ out){
  __shared__ short bufX[128 * 128];
  __shared__ short bufM[128 * 128];
  const int t = threadIdx.x, lane = t & 63, wid = t >> 6;
  const int b = blockIdx.y;
  const int s0 = blockIdx.x * 128;
  const int wm = (wid >> 1) * 64, wn = (wid & 1) * 64;
  const f32x4 z = {0.f, 0.f, 0.f, 0.f};

  stage_rows<128>(x + ((size_t)b * SS + s0) * DD, bufX, t);
  stage_rows<128>(Mt + (size_t)b * DD * DD, bufM, t);
  __syncthreads();

  f32x4 acc[4][4];
  #pragma unroll
  for (int i = 0; i < 4; ++i)
    #pragma unroll
    for (int j = 0; j < 4; ++j) acc[i][j] = z;
  wave_gemm64(bufX, bufM, wm, wn, lane, acc);

  float* ob = out + ((size_t)b * SS + s0) * DD;
  #pragma unroll
  for (int mt = 0; mt < 4; ++mt)
    #pragma unroll
    for (int nt = 0; nt < 4; ++nt)
      #pragma unroll
      for (int i = 0; i < 4; ++i){
        int sp = wm + mt * 16 + ((lane >> 4) << 2) + i;
        int g = wn + nt * 16 + (lane & 15);
        ob[(sp << 7) + g] = acc[mt][nt][i];
      }
}

extern "C" void kernel_launch(void* const* d_in, const int* in_sizes, int n_in,
                              void* d_out, int out_size, void* d_ws, size_t ws_size,
                              hipStream_t stream) {
  const float* x   = (const float*)d_in[0];
  const float* Wkq = (const float*)d_in[1];
  const float* Wv  = (const float*)d_in[2];
  float* out = (float*)d_out;

  float* G  = (float*)d_ws;                       // [B][128][128] fp32
  float* Mt = G + (size_t)BB * DD * DD;           // [B][128][128] fp32 (M transposed)

  hipMemsetAsync(d_ws, 0, (size_t)2 * BB * DD * DD * sizeof(float), stream);
  k_gram <<<dim3(8, BB),  256, 0, stream>>>(x, G);
  k_heads<<<dim3(HH, BB), 256, 0, stream>>>(G, Wkq, Wv, Mt);
  k_out  <<<dim3(SS / 128, BB), 256, 0, stream>>>(x, Mt, out);
}

// Round 2
// 159.828 us; speedup vs baseline: 1.6880x; 1.6880x over previous
//
#include <hip/hip_runtime.h>
#include <hip/hip_bf16.h>

#define BB 32
#define SS 4096
#define DD 128
#define HH 8

typedef __attribute__((ext_vector_type(8))) short short8;   // 8 bf16 (MFMA A/B frag)
typedef __attribute__((ext_vector_type(4))) float f32x4;    // MFMA C/D frag
typedef unsigned long long u64;

// fp32 -> bf16 round-to-nearest-even (bit pattern)
__device__ inline unsigned short f2b(float f){
  unsigned int u = __float_as_uint(f);
  return (unsigned short)((u + 0x7fffu + ((u >> 16) & 1u)) >> 16);
}

// Swizzled element index in a [R][128] bf16 LDS tile (16B blocks XOR row&7).
__device__ inline int swzi(int r, int c){
  return (r << 7) | (((c >> 3) ^ (r & 7)) << 3) | (c & 7);
}

// MFMA A/B fragment read: lane -> row (base + l&15), 8 consecutive k at kblk*8.
__device__ inline short8 ldfrag(const short* buf, int row, int kblk){
  return *reinterpret_cast<const short8*>(&buf[(row << 7) | ((kblk ^ (row & 7)) << 3)]);
}

// 32x64 wave tile: C[wm..+31][wn..+63] += A(rows of bufA) * B^T(rows of bufB), K=128
__device__ inline void wave_gemm32x64(const short* bufA, const short* bufB,
                                      int wm, int wn, int lane, f32x4 acc[2][4]){
  #pragma unroll
  for (int ks = 0; ks < 4; ++ks){
    int kblk = ks * 4 + (lane >> 4);
    short8 af[2], bf[4];
    #pragma unroll
    for (int mt = 0; mt < 2; ++mt) af[mt] = ldfrag(bufA, wm + mt * 16 + (lane & 15), kblk);
    #pragma unroll
    for (int nt = 0; nt < 4; ++nt) bf[nt] = ldfrag(bufB, wn + nt * 16 + (lane & 15), kblk);
    #pragma unroll
    for (int mt = 0; mt < 2; ++mt)
      #pragma unroll
      for (int nt = 0; nt < 4; ++nt)
        acc[mt][nt] = __builtin_amdgcn_mfma_f32_16x16x32_bf16(af[mt], bf[nt], acc[mt][nt], 0, 0, 0);
  }
}

__device__ inline u64 packb4(float a, float b, float c, float d){
  return (u64)f2b(a) | ((u64)f2b(b) << 16) | ((u64)f2b(c) << 32) | ((u64)f2b(d) << 48);
}

// fp32 [128][128] row-major -> swizzled bf16 LDS. NT = thread count.
template<int NT>
__device__ inline void stage128(const float* __restrict__ src, short* dst, int t){
  const float4* s4 = reinterpret_cast<const float4*>(src);
  #pragma unroll
  for (int f4 = t; f4 < 4096; f4 += NT){
    int r = f4 >> 5, c = (f4 & 31) << 2;
    float4 v = s4[f4];
    *reinterpret_cast<u64*>(&dst[swzi(r, c)]) = packb4(v.x, v.y, v.z, v.w);
  }
}

// reg-staged variant (issue-early / write-late), NT=512: 8 float4 per thread
__device__ inline void ld128(const float* __restrict__ src, int t, float4 r[8]){
  const float4* s4 = reinterpret_cast<const float4*>(src);
  #pragma unroll
  for (int i = 0; i < 8; ++i) r[i] = s4[t + i * 512];
}
__device__ inline void wr128(short* dst, int t, const float4 r[8]){
  #pragma unroll
  for (int i = 0; i < 8; ++i){
    int f4 = t + i * 512;
    int rr = f4 >> 5, c = (f4 & 31) << 2;
    *reinterpret_cast<u64*>(&dst[swzi(rr, c)]) = packb4(r[i].x, r[i].y, r[i].z, r[i].w);
  }
}

// ---------------- Kernel 1: Gp[slot][b] = partial x[b]^T x[b] over 512 s-rows ----------------
// grid (8, B), 512 threads. Reg-pipelined transpose staging, no atomics.
__global__ __launch_bounds__(512) void k_gram(const float* __restrict__ x, float* __restrict__ Gp){
  __shared__ short xsT[128 * 128];   // 32 KB
  const int t = threadIdx.x, lane = t & 63, wid = t >> 6;
  const int slot = blockIdx.x, b = blockIdx.y;
  const int e = t & 127, sg = t >> 7;             // sg in [0,4)
  const int wm = (wid >> 1) * 32, wn = (wid & 1) * 64;

  f32x4 acc[2][4];
  const f32x4 z = {0.f, 0.f, 0.f, 0.f};
  #pragma unroll
  for (int i = 0; i < 2; ++i)
    #pragma unroll
    for (int j = 0; j < 4; ++j) acc[i][j] = z;

  const float* xb = x + ((size_t)b * SS + slot * 512) * DD;
  float r0[16], r1[16];
  // prologue: issue chunk-0 loads (column e of 128 rows, coalesced across lanes)
  #pragma unroll
  for (int i = 0; i < 16; ++i){
    int s2 = sg + 4 * i;
    r0[i] = xb[(2 * s2) * DD + e];
    r1[i] = xb[(2 * s2 + 1) * DD + e];
  }
  for (int c = 0; c < 4; ++c){
    __syncthreads();                 // previous gemm's reads of xsT done
    #pragma unroll
    for (int i = 0; i < 16; ++i){    // transposed packed writes (vmcnt auto-waited)
      int s2 = sg + 4 * i;
      unsigned int w = (unsigned)f2b(r0[i]) | ((unsigned)f2b(r1[i]) << 16);
      *reinterpret_cast<unsigned int*>(&xsT[swzi(e, 2 * s2)]) = w;
    }
    if (c < 3){                      // issue next chunk: in flight across gemm below
      const float* src = xb + (size_t)(c + 1) * 128 * DD;
      #pragma unroll
      for (int i = 0; i < 16; ++i){
        int s2 = sg + 4 * i;
        r0[i] = src[(2 * s2) * DD + e];
        r1[i] = src[(2 * s2 + 1) * DD + e];
      }
    }
    __syncthreads();
    wave_gemm32x64(xsT, xsT, wm, wn, lane, acc);
  }

  float* Gb = Gp + (size_t)(slot * BB + b) * (DD * DD);
  #pragma unroll
  for (int mt = 0; mt < 2; ++mt)
    #pragma unroll
    for (int nt = 0; nt < 4; ++nt)
      #pragma unroll
      for (int i = 0; i < 4; ++i){
        int ee = wm + mt * 16 + ((lane >> 4) << 2) + i;
        int ff = wn + nt * 16 + (lane & 15);
        Gb[(ee << 7) + ff] = acc[mt][nt][i];     // plain coalesced store
      }
}

// ---------------- Kernel 2: Mp[h][b][g][d] = (Wkq[h] G[b] Wv[h]^T)^T ----------------
// grid (H, B), 512 threads. G staged as sum of 8 slot partials. No atomics.
__global__ __launch_bounds__(512) void k_heads(const float* __restrict__ Gp,
                                               const float* __restrict__ Wkq,
                                               const float* __restrict__ Wv,
                                               float* __restrict__ Mp){
  __shared__ short bufW[128 * 128];
  __shared__ short bufG[128 * 128];
  __shared__ short bufT[128 * 128];
  const int t = threadIdx.x, lane = t & 63, wid = t >> 6;
  const int h = blockIdx.x, b = blockIdx.y;
  const int wm = (wid >> 1) * 32, wn = (wid & 1) * 64;
  const f32x4 z = {0.f, 0.f, 0.f, 0.f};

  stage128<512>(Wv + (size_t)h * DD * DD, bufW, t);
  {  // G = sum of 8 slot partials (hot in L2/L3)
    const float4* g4 = reinterpret_cast<const float4*>(Gp);
    #pragma unroll
    for (int it = 0; it < 8; ++it){
      int f4 = t + it * 512;
      float4 s = {0.f, 0.f, 0.f, 0.f};
      #pragma unroll
      for (int sl = 0; sl < 8; ++sl){
        float4 v = g4[(size_t)(sl * BB + b) * 4096 + f4];
        s.x += v.x; s.y += v.y; s.z += v.z; s.w += v.w;
      }
      int r = f4 >> 5, c = (f4 & 31) << 2;
      *reinterpret_cast<u64*>(&bufG[swzi(r, c)]) = packb4(s.x, s.y, s.z, s.w);
    }
  }
  __syncthreads();

  float4 wk[8];
  ld128(Wkq + (size_t)h * DD * DD, t, wk);   // early issue, lands during gemm1

  f32x4 acc[2][4];
  #pragma unroll
  for (int i = 0; i < 2; ++i)
    #pragma unroll
    for (int j = 0; j < 4; ++j) acc[i][j] = z;
  // Tt[g][e] = sum_f Wv[g][f] * G[e][f]   (G symmetric)
  wave_gemm32x64(bufW, bufG, wm, wn, lane, acc);
  __syncthreads();                            // all gemm1 reads done before overwrite

  #pragma unroll
  for (int mt = 0; mt < 2; ++mt)
    #pragma unroll
    for (int nt = 0; nt < 4; ++nt)
      #pragma unroll
      for (int i = 0; i < 4; ++i){
        int g = wm + mt * 16 + ((lane >> 4) << 2) + i;
        int e = wn + nt * 16 + (lane & 15);
        bufT[swzi(g, e)] = (short)f2b(acc[mt][nt][i]);
      }
  wr128(bufW, t, wk);                         // Wkq into bufW
  __syncthreads();

  #pragma unroll
  for (int i = 0; i < 2; ++i)
    #pragma unroll
    for (int j = 0; j < 4; ++j) acc[i][j] = z;
  // Mt[g][d] = sum_e Tt[g][e] * Wkq[d][e]  (operand swap -> transposed result, coalesced store)
  wave_gemm32x64(bufT, bufW, wm, wn, lane, acc);

  float* Mb = Mp + (size_t)(h * BB + b) * (DD * DD);
  #pragma unroll
  for (int mt = 0; mt < 2; ++mt)
    #pragma unroll
    for (int nt = 0; nt < 4; ++nt)
      #pragma unroll
      for (int i = 0; i < 4; ++i){
        int g = wm + mt * 16 + ((lane >> 4) << 2) + i;
        int d = wn + nt * 16 + (lane & 15);
        Mb[(g << 7) + d] = acc[mt][nt][i];
      }
}

// ---------------- Kernel 3: Mbf[b][g][d] = bf16( sum_h Mp[h][b][g][d] ) ----------------
__global__ __launch_bounds__(256) void k_red(const float* __restrict__ Mp, short* __restrict__ Mb){
  const int id = blockIdx.x * 256 + threadIdx.x;
  const float4* p4 = reinterpret_cast<const float4*>(Mp);
  u64* o8 = reinterpret_cast<u64*>(Mb);
  #pragma unroll
  for (int it = 0; it < 4; ++it){
    int F = id + it * 32768;                 // 131072 float4-outputs total
    int b = F >> 12, j4 = F & 4095;
    float4 s = {0.f, 0.f, 0.f, 0.f};
    #pragma unroll
    for (int hh = 0; hh < 8; ++hh){
      float4 v = p4[(size_t)(hh * BB + b) * 4096 + j4];
      s.x += v.x; s.y += v.y; s.z += v.z; s.w += v.w;
    }
    o8[F] = packb4(s.x, s.y, s.z, s.w);
  }
}

// ---------------- Kernel 4: out[b][s][g] = sum_d x[b][s][d] * Mt[b][g][d] ----------------
// grid (S/256, B), 512 threads, 2 chunks with reg-pipelined x staging.
__global__ __launch_bounds__(512) void k_out(const float* __restrict__ x,
                                             const short* __restrict__ Mbf,
                                             float* __restrict__ out){
  __shared__ short bufM[128 * 128];
  __shared__ short bufX[128 * 128];
  const int t = threadIdx.x, lane = t & 63, wid = t >> 6;
  const int b = blockIdx.y, s0 = blockIdx.x * 256;
  const int wm = (wid >> 1) * 32, wn = (wid & 1) * 64;
  const f32x4 z = {0.f, 0.f, 0.f, 0.f};

  {  // stage M^T (already bf16): b128 copy into swizzled layout
    const short8* m8 = reinterpret_cast<const short8*>(Mbf + (size_t)b * DD * DD);
    #pragma unroll
    for (int i = 0; i < 4; ++i){
      int idx = t + i * 512;                 // 2048 groups of 8 bf16
      int r = idx >> 4, c8 = idx & 15;
      *reinterpret_cast<short8*>(&bufM[(r << 7) | ((c8 ^ (r & 7)) << 3)]) = m8[idx];
    }
  }
  const float* xb = x + ((size_t)b * SS + s0) * DD;
  float4 xr[8];
  ld128(xb, t, xr);                          // chunk 0 in flight

  for (int c = 0; c < 2; ++c){
    __syncthreads();                         // bufX free (and M staged, first iter)
    wr128(bufX, t, xr);
    if (c < 1) ld128(xb + (size_t)128 * DD, t, xr);   // chunk 1 in flight across gemm(0)
    __syncthreads();

    f32x4 acc[2][4];
    #pragma unroll
    for (int i = 0; i < 2; ++i)
      #pragma unroll
      for (int j = 0; j < 4; ++j) acc[i][j] = z;
    wave_gemm32x64(bufX, bufM, wm, wn, lane, acc);

    float* ob = out + ((size_t)b * SS + s0 + c * 128) * DD;
    #pragma unroll
    for (int mt = 0; mt < 2; ++mt)
      #pragma unroll
      for (int nt = 0; nt < 4; ++nt)
        #pragma unroll
        for (int i = 0; i < 4; ++i){
          int sp = wm + mt * 16 + ((lane >> 4) << 2) + i;
          int g = wn + nt * 16 + (lane & 15);
          ob[(sp << 7) + g] = acc[mt][nt][i];
        }
  }
}

extern "C" void kernel_launch(void* const* d_in, const int* in_sizes, int n_in,
                              void* d_out, int out_size, void* d_ws, size_t ws_size,
                              hipStream_t stream) {
  const float* x   = (const float*)d_in[0];
  const float* Wkq = (const float*)d_in[1];
  const float* Wv  = (const float*)d_in[2];
  float* out = (float*)d_out;

  float* Gp = (float*)d_ws;                            // 8 slots * [B][128][128] fp32 = 16 MB
  float* Mp = Gp + (size_t)8 * BB * DD * DD;           // 8 heads * [B][128][128] fp32 = 16 MB
  short* Mb = (short*)(Mp + (size_t)HH * BB * DD * DD);// [B][128][128] bf16 = 1 MB

  k_gram <<<dim3(8, BB),       512, 0, stream>>>(x, Gp);
  k_heads<<<dim3(HH, BB),      512, 0, stream>>>(Gp, Wkq, Wv, Mp);
  k_red  <<<dim3(128),         256, 0, stream>>>(Mp, Mb);
  k_out  <<<dim3(SS / 256, BB), 512, 0, stream>>>(x, Mb, out);
}

// Round 3
// 152.157 us; speedup vs baseline: 1.7731x; 1.0504x over previous
//
#include <hip/hip_runtime.h>
#include <hip/hip_bf16.h>

#define BB 32
#define SS 4096
#define DD 128
#define HH 8

typedef __attribute__((ext_vector_type(8))) short short8;   // 8 bf16 (MFMA A/B frag)
typedef __attribute__((ext_vector_type(4))) float f32x4;    // MFMA C/D frag
typedef unsigned long long u64;

// fp32 -> bf16 round-to-nearest-even (bit pattern)
__device__ inline unsigned short f2b(float f){
  unsigned int u = __float_as_uint(f);
  return (unsigned short)((u + 0x7fffu + ((u >> 16) & 1u)) >> 16);
}

// Swizzled element index in a [R][128] bf16 LDS tile (16B blocks XOR row&7).
__device__ inline int swzi(int r, int c){
  return (r << 7) | (((c >> 3) ^ (r & 7)) << 3) | (c & 7);
}

// MFMA A/B fragment read from swizzled LDS tile.
__device__ inline short8 ldfrag(const short* buf, int row, int kblk){
  return *reinterpret_cast<const short8*>(&buf[(row << 7) | ((kblk ^ (row & 7)) << 3)]);
}

// MFMA A fragment DIRECT from row-major fp32 global (no LDS): lane -> row,
// 8 consecutive d at kblk*8. Wave-wide: 16 rows x 128B contiguous per (mt,ks).
__device__ inline short8 ldxfrag(const float* __restrict__ base, int row, int kblk){
  const float4* p = reinterpret_cast<const float4*>(base) + row * 32 + kblk * 2;
  float4 a = p[0], b = p[1];
  short8 r;
  r[0] = (short)f2b(a.x); r[1] = (short)f2b(a.y); r[2] = (short)f2b(a.z); r[3] = (short)f2b(a.w);
  r[4] = (short)f2b(b.x); r[5] = (short)f2b(b.y); r[6] = (short)f2b(b.z); r[7] = (short)f2b(b.w);
  return r;
}

// 32x64 wave tile: C[wm..+31][wn..+63] += A(rows of bufA) * B^T(rows of bufB), K=128
__device__ inline void wave_gemm32x64(const short* bufA, const short* bufB,
                                      int wm, int wn, int lane, f32x4 acc[2][4]){
  #pragma unroll
  for (int ks = 0; ks < 4; ++ks){
    int kblk = ks * 4 + (lane >> 4);
    short8 af[2], bf[4];
    #pragma unroll
    for (int mt = 0; mt < 2; ++mt) af[mt] = ldfrag(bufA, wm + mt * 16 + (lane & 15), kblk);
    #pragma unroll
    for (int nt = 0; nt < 4; ++nt) bf[nt] = ldfrag(bufB, wn + nt * 16 + (lane & 15), kblk);
    #pragma unroll
    for (int mt = 0; mt < 2; ++mt)
      #pragma unroll
      for (int nt = 0; nt < 4; ++nt)
        acc[mt][nt] = __builtin_amdgcn_mfma_f32_16x16x32_bf16(af[mt], bf[nt], acc[mt][nt], 0, 0, 0);
  }
}

__device__ inline u64 packb4(float a, float b, float c, float d){
  return (u64)f2b(a) | ((u64)f2b(b) << 16) | ((u64)f2b(c) << 32) | ((u64)f2b(d) << 48);
}

// fp32 [128][128] row-major -> swizzled bf16 LDS. NT = thread count.
template<int NT>
__device__ inline void stage128(const float* __restrict__ src, short* dst, int t){
  const float4* s4 = reinterpret_cast<const float4*>(src);
  #pragma unroll
  for (int f4 = t; f4 < 4096; f4 += NT){
    int r = f4 >> 5, c = (f4 & 31) << 2;
    float4 v = s4[f4];
    *reinterpret_cast<u64*>(&dst[swzi(r, c)]) = packb4(v.x, v.y, v.z, v.w);
  }
}

// reg-staged variant (issue-early / write-late), NT=512: 8 float4 per thread
__device__ inline void ld128(const float* __restrict__ src, int t, float4 r[8]){
  const float4* s4 = reinterpret_cast<const float4*>(src);
  #pragma unroll
  for (int i = 0; i < 8; ++i) r[i] = s4[t + i * 512];
}
__device__ inline void wr128(short* dst, int t, const float4 r[8]){
  #pragma unroll
  for (int i = 0; i < 8; ++i){
    int f4 = t + i * 512;
    int rr = f4 >> 5, c = (f4 & 31) << 2;
    *reinterpret_cast<u64*>(&dst[swzi(rr, c)]) = packb4(r[i].x, r[i].y, r[i].z, r[i].w);
  }
}

// ---------------- Kernel 1: Gp[slot][b] = partial x[b]^T x[b] over 512 s-rows ----------------
__global__ __launch_bounds__(512) void k_gram(const float* __restrict__ x, float* __restrict__ Gp){
  __shared__ short xsT[128 * 128];   // 32 KB
  const int t = threadIdx.x, lane = t & 63, wid = t >> 6;
  const int slot = blockIdx.x, b = blockIdx.y;
  const int e = t & 127, sg = t >> 7;             // sg in [0,4)
  const int wm = (wid >> 1) * 32, wn = (wid & 1) * 64;

  f32x4 acc[2][4];
  const f32x4 z = {0.f, 0.f, 0.f, 0.f};
  #pragma unroll
  for (int i = 0; i < 2; ++i)
    #pragma unroll
    for (int j = 0; j < 4; ++j) acc[i][j] = z;

  const float* xb = x + ((size_t)b * SS + slot * 512) * DD;
  float r0[16], r1[16];
  #pragma unroll
  for (int i = 0; i < 16; ++i){
    int s2 = sg + 4 * i;
    r0[i] = xb[(2 * s2) * DD + e];
    r1[i] = xb[(2 * s2 + 1) * DD + e];
  }
  for (int c = 0; c < 4; ++c){
    __syncthreads();                 // previous gemm's reads of xsT done
    #pragma unroll
    for (int i = 0; i < 16; ++i){
      int s2 = sg + 4 * i;
      unsigned int w = (unsigned)f2b(r0[i]) | ((unsigned)f2b(r1[i]) << 16);
      *reinterpret_cast<unsigned int*>(&xsT[swzi(e, 2 * s2)]) = w;
    }
    if (c < 3){                      // issue next chunk: in flight across gemm below
      const float* src = xb + (size_t)(c + 1) * 128 * DD;
      #pragma unroll
      for (int i = 0; i < 16; ++i){
        int s2 = sg + 4 * i;
        r0[i] = src[(2 * s2) * DD + e];
        r1[i] = src[(2 * s2 + 1) * DD + e];
      }
    }
    __syncthreads();
    wave_gemm32x64(xsT, xsT, wm, wn, lane, acc);
  }

  float* Gb = Gp + (size_t)(slot * BB + b) * (DD * DD);
  #pragma unroll
  for (int mt = 0; mt < 2; ++mt)
    #pragma unroll
    for (int nt = 0; nt < 4; ++nt)
      #pragma unroll
      for (int i = 0; i < 4; ++i){
        int ee = wm + mt * 16 + ((lane >> 4) << 2) + i;
        int ff = wn + nt * 16 + (lane & 15);
        Gb[(ee << 7) + ff] = acc[mt][nt][i];
      }
}

// ---------------- Kernel 2: Gbf[b] = bf16-swizzled-image( sum_slot Gp[slot][b] ) ----------------
__global__ __launch_bounds__(256) void k_gsum(const float* __restrict__ Gp, short* __restrict__ Gbf){
  const int id = blockIdx.x * 256 + threadIdx.x;
  const float4* g4 = reinterpret_cast<const float4*>(Gp);
  #pragma unroll
  for (int it = 0; it < 4; ++it){
    int F = id + it * 32768;                 // 131072 float4 outputs total
    int b = F >> 12, j4 = F & 4095;
    float4 s = {0.f, 0.f, 0.f, 0.f};
    #pragma unroll
    for (int sl = 0; sl < 8; ++sl){
      float4 v = g4[(size_t)(sl * BB + b) * 4096 + j4];
      s.x += v.x; s.y += v.y; s.z += v.z; s.w += v.w;
    }
    int r = j4 >> 5, c = (j4 & 31) << 2;
    *reinterpret_cast<u64*>(&Gbf[(size_t)b * 16384 + swzi(r, c)]) = packb4(s.x, s.y, s.z, s.w);
  }
}

// ---------------- Kernel 3: Mp[h][b][g][d] = (Wkq[h] G[b] Wv[h]^T)^T ----------------
__global__ __launch_bounds__(512) void k_heads(const short* __restrict__ Gbf,
                                               const float* __restrict__ Wkq,
                                               const float* __restrict__ Wv,
                                               float* __restrict__ Mp){
  __shared__ short bufW[128 * 128];
  __shared__ short bufG[128 * 128];
  __shared__ short bufT[128 * 128];
  const int t = threadIdx.x, lane = t & 63, wid = t >> 6;
  const int h = blockIdx.x, b = blockIdx.y;
  const int wm = (wid >> 1) * 32, wn = (wid & 1) * 64;
  const f32x4 z = {0.f, 0.f, 0.f, 0.f};

  stage128<512>(Wv + (size_t)h * DD * DD, bufW, t);
  {  // G: plain 32 KB copy (image already bf16 + swizzled)
    const short8* g8 = reinterpret_cast<const short8*>(Gbf + (size_t)b * 16384);
    short8* d8 = reinterpret_cast<short8*>(bufG);
    #pragma unroll
    for (int i = 0; i < 4; ++i) d8[t + i * 512] = g8[t + i * 512];
  }
  __syncthreads();

  float4 wk[8];
  ld128(Wkq + (size_t)h * DD * DD, t, wk);   // early issue, lands during gemm1

  f32x4 acc[2][4];
  #pragma unroll
  for (int i = 0; i < 2; ++i)
    #pragma unroll
    for (int j = 0; j < 4; ++j) acc[i][j] = z;
  // Tt[g][e] = sum_f Wv[g][f] * G[e][f]   (G symmetric)
  wave_gemm32x64(bufW, bufG, wm, wn, lane, acc);
  __syncthreads();                            // all gemm1 reads done before overwrite

  #pragma unroll
  for (int mt = 0; mt < 2; ++mt)
    #pragma unroll
    for (int nt = 0; nt < 4; ++nt)
      #pragma unroll
      for (int i = 0; i < 4; ++i){
        int g = wm + mt * 16 + ((lane >> 4) << 2) + i;
        int e = wn + nt * 16 + (lane & 15);
        bufT[swzi(g, e)] = (short)f2b(acc[mt][nt][i]);
      }
  wr128(bufW, t, wk);                         // Wkq into bufW
  __syncthreads();

  #pragma unroll
  for (int i = 0; i < 2; ++i)
    #pragma unroll
    for (int j = 0; j < 4; ++j) acc[i][j] = z;
  // Mt[g][d] = sum_e Tt[g][e] * Wkq[d][e]  (swap -> transposed result, coalesced store)
  wave_gemm32x64(bufT, bufW, wm, wn, lane, acc);

  float* Mb = Mp + (size_t)(h * BB + b) * (DD * DD);
  #pragma unroll
  for (int mt = 0; mt < 2; ++mt)
    #pragma unroll
    for (int nt = 0; nt < 4; ++nt)
      #pragma unroll
      for (int i = 0; i < 4; ++i){
        int g = wm + mt * 16 + ((lane >> 4) << 2) + i;
        int d = wn + nt * 16 + (lane & 15);
        Mb[(g << 7) + d] = acc[mt][nt][i];
      }
}

// ---------------- Kernel 4: Mbf[b][g][d] = bf16( sum_h Mp[h][b][g][d] ) ----------------
__global__ __launch_bounds__(256) void k_red(const float* __restrict__ Mp, short* __restrict__ Mb){
  const int id = blockIdx.x * 256 + threadIdx.x;
  const float4* p4 = reinterpret_cast<const float4*>(Mp);
  u64* o8 = reinterpret_cast<u64*>(Mb);
  #pragma unroll
  for (int it = 0; it < 4; ++it){
    int F = id + it * 32768;
    int b = F >> 12, j4 = F & 4095;
    float4 s = {0.f, 0.f, 0.f, 0.f};
    #pragma unroll
    for (int hh = 0; hh < 8; ++hh){
      float4 v = p4[(size_t)(hh * BB + b) * 4096 + j4];
      s.x += v.x; s.y += v.y; s.z += v.z; s.w += v.w;
    }
    o8[F] = packb4(s.x, s.y, s.z, s.w);
  }
}

// ---------------- Kernel 5: out[b][s][g] = sum_d x[b][s][d] * Mt[b][g][d] ----------------
// A-fragments DIRECT from global fp32 x (row-major == fragment layout). One barrier.
__global__ __launch_bounds__(512) void k_out(const float* __restrict__ x,
                                             const short* __restrict__ Mbf,
                                             float* __restrict__ out){
  __shared__ short bufM[128 * 128];
  const int t = threadIdx.x, lane = t & 63, wid = t >> 6;
  const int b = blockIdx.y, s0 = blockIdx.x * 256;
  const int wm = (wid >> 1) * 32, wn = (wid & 1) * 64;
  const f32x4 z = {0.f, 0.f, 0.f, 0.f};

  {  // stage M^T (bf16): b128 copy into swizzled layout
    const short8* m8 = reinterpret_cast<const short8*>(Mbf + (size_t)b * DD * DD);
    #pragma unroll
    for (int i = 0; i < 4; ++i){
      int idx = t + i * 512;
      int r = idx >> 4, c8 = idx & 15;
      *reinterpret_cast<short8*>(&bufM[(r << 7) | ((c8 ^ (r & 7)) << 3)]) = m8[idx];
    }
  }
  __syncthreads();

  const float* xb = x + ((size_t)b * SS + s0) * DD;
  #pragma unroll
  for (int c = 0; c < 2; ++c){
    f32x4 acc[2][4];
    #pragma unroll
    for (int i = 0; i < 2; ++i)
      #pragma unroll
      for (int j = 0; j < 4; ++j) acc[i][j] = z;

    #pragma unroll
    for (int ks = 0; ks < 4; ++ks){
      int kblk = ks * 4 + (lane >> 4);
      short8 af[2], bf[4];
      #pragma unroll
      for (int mt = 0; mt < 2; ++mt)
        af[mt] = ldxfrag(xb, c * 128 + wm + mt * 16 + (lane & 15), kblk);
      #pragma unroll
      for (int nt = 0; nt < 4; ++nt) bf[nt] = ldfrag(bufM, wn + nt * 16 + (lane & 15), kblk);
      #pragma unroll
      for (int mt = 0; mt < 2; ++mt)
        #pragma unroll
        for (int nt = 0; nt < 4; ++nt)
          acc[mt][nt] = __builtin_amdgcn_mfma_f32_16x16x32_bf16(af[mt], bf[nt], acc[mt][nt], 0, 0, 0);
    }

    float* ob = out + ((size_t)b * SS + s0 + c * 128) * DD;
    #pragma unroll
    for (int mt = 0; mt < 2; ++mt)
      #pragma unroll
      for (int nt = 0; nt < 4; ++nt)
        #pragma unroll
        for (int i = 0; i < 4; ++i){
          int sp = wm + mt * 16 + ((lane >> 4) << 2) + i;
          int g = wn + nt * 16 + (lane & 15);
          ob[(sp << 7) + g] = acc[mt][nt][i];
        }
  }
}

extern "C" void kernel_launch(void* const* d_in, const int* in_sizes, int n_in,
                              void* d_out, int out_size, void* d_ws, size_t ws_size,
                              hipStream_t stream) {
  const float* x   = (const float*)d_in[0];
  const float* Wkq = (const float*)d_in[1];
  const float* Wv  = (const float*)d_in[2];
  float* out = (float*)d_out;

  float* Gp  = (float*)d_ws;                            // 8 * [B][128][128] fp32 = 16 MB
  float* Mp  = Gp + (size_t)8 * BB * DD * DD;           // 8 * [B][128][128] fp32 = 16 MB
  short* Gbf = (short*)(Mp + (size_t)HH * BB * DD * DD);// [B][16384] bf16 swizzled = 1 MB
  short* Mb  = Gbf + (size_t)BB * DD * DD;              // [B][128][128] bf16 = 1 MB

  k_gram <<<dim3(8, BB),        512, 0, stream>>>(x, Gp);
  k_gsum <<<dim3(128),          256, 0, stream>>>(Gp, Gbf);
  k_heads<<<dim3(HH, BB),       512, 0, stream>>>(Gbf, Wkq, Wv, Mp);
  k_red  <<<dim3(128),          256, 0, stream>>>(Mp, Mb);
  k_out  <<<dim3(SS / 256, BB), 512, 0, stream>>>(x, Mb, out);
}

// Round 4
// 149.808 us; speedup vs baseline: 1.8009x; 1.0157x over previous
//
#include <hip/hip_runtime.h>
#include <hip/hip_bf16.h>

#define BB 32
#define SS 4096
#define DD 128
#define HH 8

typedef __attribute__((ext_vector_type(8))) short short8;   // 8 bf16 (MFMA A/B frag)
typedef __attribute__((ext_vector_type(4))) float f32x4;    // MFMA C/D frag
typedef unsigned long long u64;

// fp32 -> bf16 round-to-nearest-even (bit pattern)
__device__ inline unsigned short f2b(float f){
  unsigned int u = __float_as_uint(f);
  return (unsigned short)((u + 0x7fffu + ((u >> 16) & 1u)) >> 16);
}

// Swizzled element index in a [R][128] bf16 LDS tile (16B blocks XOR row&7).
__device__ inline int swzi(int r, int c){
  return (r << 7) | (((c >> 3) ^ (r & 7)) << 3) | (c & 7);
}

// MFMA A/B fragment read from swizzled LDS tile.
__device__ inline short8 ldfrag(const short* buf, int row, int kblk){
  return *reinterpret_cast<const short8*>(&buf[(row << 7) | ((kblk ^ (row & 7)) << 3)]);
}

// MFMA A fragment DIRECT from row-major fp32 global (no LDS): lane -> row,
// 8 consecutive d at kblk*8.
__device__ inline short8 ldxfrag(const float* __restrict__ base, int row, int kblk){
  const float4* p = reinterpret_cast<const float4*>(base) + row * 32 + kblk * 2;
  float4 a = p[0], b = p[1];
  short8 r;
  r[0] = (short)f2b(a.x); r[1] = (short)f2b(a.y); r[2] = (short)f2b(a.z); r[3] = (short)f2b(a.w);
  r[4] = (short)f2b(b.x); r[5] = (short)f2b(b.y); r[6] = (short)f2b(b.z); r[7] = (short)f2b(b.w);
  return r;
}

// 32x64 wave tile: C[wm..+31][wn..+63] += A(rows of bufA) * B^T(rows of bufB), K=128
__device__ inline void wave_gemm32x64(const short* bufA, const short* bufB,
                                      int wm, int wn, int lane, f32x4 acc[2][4]){
  #pragma unroll
  for (int ks = 0; ks < 4; ++ks){
    int kblk = ks * 4 + (lane >> 4);
    short8 af[2], bf[4];
    #pragma unroll
    for (int mt = 0; mt < 2; ++mt) af[mt] = ldfrag(bufA, wm + mt * 16 + (lane & 15), kblk);
    #pragma unroll
    for (int nt = 0; nt < 4; ++nt) bf[nt] = ldfrag(bufB, wn + nt * 16 + (lane & 15), kblk);
    #pragma unroll
    for (int mt = 0; mt < 2; ++mt)
      #pragma unroll
      for (int nt = 0; nt < 4; ++nt)
        acc[mt][nt] = __builtin_amdgcn_mfma_f32_16x16x32_bf16(af[mt], bf[nt], acc[mt][nt], 0, 0, 0);
  }
}

// 32x32 wave tile (for k_heads split-g): acc[2][2]
__device__ inline void wave_gemm32x32(const short* bufA, const short* bufB,
                                      int wm, int wn, int lane, f32x4 acc[2][2]){
  #pragma unroll
  for (int ks = 0; ks < 4; ++ks){
    int kblk = ks * 4 + (lane >> 4);
    short8 af[2], bf[2];
    #pragma unroll
    for (int mt = 0; mt < 2; ++mt) af[mt] = ldfrag(bufA, wm + mt * 16 + (lane & 15), kblk);
    #pragma unroll
    for (int nt = 0; nt < 2; ++nt) bf[nt] = ldfrag(bufB, wn + nt * 16 + (lane & 15), kblk);
    #pragma unroll
    for (int mt = 0; mt < 2; ++mt)
      #pragma unroll
      for (int nt = 0; nt < 2; ++nt)
        acc[mt][nt] = __builtin_amdgcn_mfma_f32_16x16x32_bf16(af[mt], bf[nt], acc[mt][nt], 0, 0, 0);
  }
}

__device__ inline u64 packb4(float a, float b, float c, float d){
  return (u64)f2b(a) | ((u64)f2b(b) << 16) | ((u64)f2b(c) << 32) | ((u64)f2b(d) << 48);
}

// fp32 [R][128] row-major -> swizzled bf16 LDS, 512 threads.
template<int R>
__device__ inline void stageR(const float* __restrict__ src, short* dst, int t){
  const float4* s4 = reinterpret_cast<const float4*>(src);
  #pragma unroll
  for (int f4 = t; f4 < R * 32; f4 += 512){
    int r = f4 >> 5, c = (f4 & 31) << 2;
    float4 v = s4[f4];
    *reinterpret_cast<u64*>(&dst[swzi(r, c)]) = packb4(v.x, v.y, v.z, v.w);
  }
}

// reg-staged variant (issue-early / write-late), 512 threads: 8 float4 per thread
__device__ inline void ld128(const float* __restrict__ src, int t, float4 r[8]){
  const float4* s4 = reinterpret_cast<const float4*>(src);
  #pragma unroll
  for (int i = 0; i < 8; ++i) r[i] = s4[t + i * 512];
}
__device__ inline void wr128(short* dst, int t, const float4 r[8]){
  #pragma unroll
  for (int i = 0; i < 8; ++i){
    int f4 = t + i * 512;
    int rr = f4 >> 5, c = (f4 & 31) << 2;
    *reinterpret_cast<u64*>(&dst[swzi(rr, c)]) = packb4(r[i].x, r[i].y, r[i].z, r[i].w);
  }
}

// ---------------- Kernel 1: Gp[slot][b] = partial x[b]^T x[b] over 512 s-rows ----------------
// Transpose staging: thread gathers 8 s-values for one e -> single ds_write_b128
// (64 lanes -> 8 disjoint 4-bank groups x 8 lanes = conflict-free minimum phases).
__global__ __launch_bounds__(512) void k_gram(const float* __restrict__ x, float* __restrict__ Gp){
  __shared__ short xsT[128 * 128];   // 32 KB, x^T chunk swizzled
  const int t = threadIdx.x, lane = t & 63, wid = t >> 6;
  const int slot = blockIdx.x, b = blockIdx.y;
  const int e = t & 127, sb0 = t >> 7;            // sb0 in [0,4): base s-block (8 s each)
  const int wm = (wid >> 1) * 32, wn = (wid & 1) * 64;

  f32x4 acc[2][4];
  const f32x4 z = {0.f, 0.f, 0.f, 0.f};
  #pragma unroll
  for (int i = 0; i < 2; ++i)
    #pragma unroll
    for (int j = 0; j < 4; ++j) acc[i][j] = z;

  const float* xb = x + ((size_t)b * SS + slot * 512) * DD;
  float v[4][8];
  // prologue: chunk-0 loads (lane-consecutive e -> coalesced 256B per row segment)
  #pragma unroll
  for (int i = 0; i < 4; ++i)
    #pragma unroll
    for (int j = 0; j < 8; ++j)
      v[i][j] = xb[(size_t)(((sb0 + 4 * i) * 8 + j)) * DD + e];

  for (int c = 0; c < 4; ++c){
    __syncthreads();                 // previous gemm's reads of xsT done
    #pragma unroll
    for (int i = 0; i < 4; ++i){     // b128 transposed writes, conflict-free
      int sb = sb0 + 4 * i;
      short8 w;
      #pragma unroll
      for (int j = 0; j < 8; ++j) w[j] = (short)f2b(v[i][j]);
      *reinterpret_cast<short8*>(&xsT[(e << 7) | ((sb ^ (e & 7)) << 3)]) = w;
    }
    if (c < 3){                      // issue next chunk: in flight across gemm below
      const float* src = xb + (size_t)(c + 1) * 128 * DD;
      #pragma unroll
      for (int i = 0; i < 4; ++i)
        #pragma unroll
        for (int j = 0; j < 8; ++j)
          v[i][j] = src[(size_t)(((sb0 + 4 * i) * 8 + j)) * DD + e];
    }
    __syncthreads();
    wave_gemm32x64(xsT, xsT, wm, wn, lane, acc);
  }

  float* Gb = Gp + (size_t)(slot * BB + b) * (DD * DD);
  #pragma unroll
  for (int mt = 0; mt < 2; ++mt)
    #pragma unroll
    for (int nt = 0; nt < 4; ++nt)
      #pragma unroll
      for (int i = 0; i < 4; ++i){
        int ee = wm + mt * 16 + ((lane >> 4) << 2) + i;
        int ff = wn + nt * 16 + (lane & 15);
        Gb[(ee << 7) + ff] = acc[mt][nt][i];
      }
}

// ---------------- Kernel 2: Gbf[b] = bf16-swizzled-image( sum_slot Gp[slot][b] ) ----------------
__global__ __launch_bounds__(256) void k_gsum(const float* __restrict__ Gp, short* __restrict__ Gbf){
  const int id = blockIdx.x * 256 + threadIdx.x;
  const float4* g4 = reinterpret_cast<const float4*>(Gp);
  #pragma unroll
  for (int it = 0; it < 4; ++it){
    int F = id + it * 32768;
    int b = F >> 12, j4 = F & 4095;
    float4 s = {0.f, 0.f, 0.f, 0.f};
    #pragma unroll
    for (int sl = 0; sl < 8; ++sl){
      float4 vv = g4[(size_t)(sl * BB + b) * 4096 + j4];
      s.x += vv.x; s.y += vv.y; s.z += vv.z; s.w += vv.w;
    }
    int r = j4 >> 5, c = (j4 & 31) << 2;
    *reinterpret_cast<u64*>(&Gbf[(size_t)b * 16384 + swzi(r, c)]) = packb4(s.x, s.y, s.z, s.w);
  }
}

// ---------------- Kernel 3: Mp[h][b][gh-half] = (Wkq[h] G[b] Wv[h]^T)^T rows [gh*64,+64) ----------------
// grid (2H, B): bx = h*2+gh. 2 LDS buffers (48 KB) -> 2 blocks/CU co-resident.
__global__ __launch_bounds__(512) void k_heads(const short* __restrict__ Gbf,
                                               const float* __restrict__ Wkq,
                                               const float* __restrict__ Wv,
                                               float* __restrict__ Mp){
  __shared__ short bufA[64 * 128];    // 16 KB: Wv-half, then Tt-half
  __shared__ short bufB[128 * 128];   // 32 KB: G, then Wkq
  const int t = threadIdx.x, lane = t & 63, wid = t >> 6;
  const int h = blockIdx.x >> 1, gh = blockIdx.x & 1, b = blockIdx.y;
  const int wm = (wid >> 2) * 32, wn = (wid & 3) * 32;
  const f32x4 z = {0.f, 0.f, 0.f, 0.f};

  stageR<64>(Wv + (size_t)h * DD * DD + (size_t)gh * 64 * DD, bufA, t);
  {  // G: plain 32 KB copy (image already bf16 + swizzled)
    const short8* g8 = reinterpret_cast<const short8*>(Gbf + (size_t)b * 16384);
    short8* d8 = reinterpret_cast<short8*>(bufB);
    #pragma unroll
    for (int i = 0; i < 4; ++i) d8[t + i * 512] = g8[t + i * 512];
  }
  __syncthreads();

  float4 wk[8];
  ld128(Wkq + (size_t)h * DD * DD, t, wk);   // early issue, lands during gemm1

  f32x4 acc[2][2];
  #pragma unroll
  for (int i = 0; i < 2; ++i)
    #pragma unroll
    for (int j = 0; j < 2; ++j) acc[i][j] = z;
  // Tt[g'][e] = sum_f Wv[gh*64+g'][f] * G[e][f]   (G symmetric)
  wave_gemm32x32(bufA, bufB, wm, wn, lane, acc);
  __syncthreads();                            // all gemm1 reads done before overwrite

  #pragma unroll
  for (int mt = 0; mt < 2; ++mt)
    #pragma unroll
    for (int nt = 0; nt < 2; ++nt)
      #pragma unroll
      for (int i = 0; i < 4; ++i){
        int g = wm + mt * 16 + ((lane >> 4) << 2) + i;
        int e = wn + nt * 16 + (lane & 15);
        bufA[swzi(g, e)] = (short)f2b(acc[mt][nt][i]);
      }
  wr128(bufB, t, wk);                         // Wkq into bufB
  __syncthreads();

  #pragma unroll
  for (int i = 0; i < 2; ++i)
    #pragma unroll
    for (int j = 0; j < 2; ++j) acc[i][j] = z;
  // Mt[g'][d] = sum_e Tt[g'][e] * Wkq[d][e]  (swap -> transposed result, coalesced store)
  wave_gemm32x32(bufA, bufB, wm, wn, lane, acc);

  float* Mb = Mp + (size_t)(h * BB + b) * (DD * DD) + (size_t)gh * 64 * DD;
  #pragma unroll
  for (int mt = 0; mt < 2; ++mt)
    #pragma unroll
    for (int nt = 0; nt < 2; ++nt)
      #pragma unroll
      for (int i = 0; i < 4; ++i){
        int g = wm + mt * 16 + ((lane >> 4) << 2) + i;
        int d = wn + nt * 16 + (lane & 15);
        Mb[(g << 7) + d] = acc[mt][nt][i];
      }
}

// ---------------- Kernel 4: Mbf[b][g][d] = bf16( sum_h Mp[h][b][g][d] ) ----------------
__global__ __launch_bounds__(256) void k_red(const float* __restrict__ Mp, short* __restrict__ Mb){
  const int id = blockIdx.x * 256 + threadIdx.x;
  const float4* p4 = reinterpret_cast<const float4*>(Mp);
  u64* o8 = reinterpret_cast<u64*>(Mb);
  #pragma unroll
  for (int it = 0; it < 4; ++it){
    int F = id + it * 32768;
    int b = F >> 12, j4 = F & 4095;
    float4 s = {0.f, 0.f, 0.f, 0.f};
    #pragma unroll
    for (int hh = 0; hh < 8; ++hh){
      float4 vv = p4[(size_t)(hh * BB + b) * 4096 + j4];
      s.x += vv.x; s.y += vv.y; s.z += vv.z; s.w += vv.w;
    }
    o8[F] = packb4(s.x, s.y, s.z, s.w);
  }
}

// ---------------- Kernel 5: out[b][s][g] = sum_d x[b][s][d] * Mt[b][g][d] ----------------
// A-fragments DIRECT from global fp32 x. One barrier (M stage).
__global__ __launch_bounds__(512) void k_out(const float* __restrict__ x,
                                             const short* __restrict__ Mbf,
                                             float* __restrict__ out){
  __shared__ short bufM[128 * 128];
  const int t = threadIdx.x, lane = t & 63, wid = t >> 6;
  const int b = blockIdx.y, s0 = blockIdx.x * 256;
  const int wm = (wid >> 1) * 32, wn = (wid & 1) * 64;
  const f32x4 z = {0.f, 0.f, 0.f, 0.f};

  {  // stage M^T (bf16): b128 copy into swizzled layout
    const short8* m8 = reinterpret_cast<const short8*>(Mbf + (size_t)b * DD * DD);
    #pragma unroll
    for (int i = 0; i < 4; ++i){
      int idx = t + i * 512;
      int r = idx >> 4, c8 = idx & 15;
      *reinterpret_cast<short8*>(&bufM[(r << 7) | ((c8 ^ (r & 7)) << 3)]) = m8[idx];
    }
  }
  __syncthreads();

  const float* xb = x + ((size_t)b * SS + s0) * DD;
  #pragma unroll
  for (int c = 0; c < 2; ++c){
    f32x4 acc[2][4];
    #pragma unroll
    for (int i = 0; i < 2; ++i)
      #pragma unroll
      for (int j = 0; j < 4; ++j) acc[i][j] = z;

    #pragma unroll
    for (int ks = 0; ks < 4; ++ks){
      int kblk = ks * 4 + (lane >> 4);
      short8 af[2], bf[4];
      #pragma unroll
      for (int mt = 0; mt < 2; ++mt)
        af[mt] = ldxfrag(xb, c * 128 + wm + mt * 16 + (lane & 15), kblk);
      #pragma unroll
      for (int nt = 0; nt < 4; ++nt) bf[nt] = ldfrag(bufM, wn + nt * 16 + (lane & 15), kblk);
      #pragma unroll
      for (int mt = 0; mt < 2; ++mt)
        #pragma unroll
        for (int nt = 0; nt < 4; ++nt)
          acc[mt][nt] = __builtin_amdgcn_mfma_f32_16x16x32_bf16(af[mt], bf[nt], acc[mt][nt], 0, 0, 0);
    }

    float* ob = out + ((size_t)b * SS + s0 + c * 128) * DD;
    #pragma unroll
    for (int mt = 0; mt < 2; ++mt)
      #pragma unroll
      for (int nt = 0; nt < 4; ++nt)
        #pragma unroll
        for (int i = 0; i < 4; ++i){
          int sp = wm + mt * 16 + ((lane >> 4) << 2) + i;
          int g = wn + nt * 16 + (lane & 15);
          ob[(sp << 7) + g] = acc[mt][nt][i];
        }
  }
}

extern "C" void kernel_launch(void* const* d_in, const int* in_sizes, int n_in,
                              void* d_out, int out_size, void* d_ws, size_t ws_size,
                              hipStream_t stream) {
  const float* x   = (const float*)d_in[0];
  const float* Wkq = (const float*)d_in[1];
  const float* Wv  = (const float*)d_in[2];
  float* out = (float*)d_out;

  float* Gp  = (float*)d_ws;                            // 8 * [B][128][128] fp32 = 16 MB
  float* Mp  = Gp + (size_t)8 * BB * DD * DD;           // 8 * [B][128][128] fp32 = 16 MB
  short* Gbf = (short*)(Mp + (size_t)HH * BB * DD * DD);// [B][16384] bf16 swizzled = 1 MB
  short* Mb  = Gbf + (size_t)BB * DD * DD;              // [B][128][128] bf16 = 1 MB

  k_gram <<<dim3(8, BB),        512, 0, stream>>>(x, Gp);
  k_gsum <<<dim3(128),          256, 0, stream>>>(Gp, Gbf);
  k_heads<<<dim3(2 * HH, BB),   512, 0, stream>>>(Gbf, Wkq, Wv, Mp);
  k_red  <<<dim3(128),          256, 0, stream>>>(Mp, Mb);
  k_out  <<<dim3(SS / 256, BB), 512, 0, stream>>>(x, Mb, out);
}